// Round 4
// baseline (459.944 us; speedup 1.0000x reference)
//
#include <hip/hip_runtime.h>
#include <climits>

// Problem constants (from reference setup_inputs)
constexpr int B = 2, C = 256, H = 200, W = 336;
constexpr int HW = H * W;
constexpr int OH = 14, OW = 14, OHW = OH * OW;   // 196 samples per ROI
constexpr float SCALE = 0.25f;
constexpr int R = 1000;

// CSPLIT=16: slices inner so all 256 channels of adjacent (bucketed) ROIs are
// co-resident on one XCD -> cross-ROI L2 reuse of overlapping rects.
constexpr int CSPLIT = 16;           // channel slices per ROI
constexpr int CPB = C / CSPLIT;      // 16 channels per block
constexpr int NXCD = 8;
constexpr int RPX = R / NXCD;        // 125 ROIs per XCD

// Bucket grid for the counting sort (locality only needs band-level order)
constexpr int NYB = 13;              // 64-px y bands over 800 px
constexpr int NXB = 21;              // 64-px x bands over 1344 px

// ROI bounding rect is provably <= 66x66 floats:
//   sample spacing sx = (x2-x1)*SCALE/OW <= 272*0.25/14 = 4.857 px
//   span = 13*sx <= 63.2  ->  cols = span+2 <= 66, rows likewise.
// Stride forced odd (rw|1 <= 67) to spread LDS banks across rows.
constexpr int RECT_ELEMS = 66 * 67;  // 4422 floats = 17.7 KB

// ---------------------------------------------------------------------------
// Kernel A: counting sort of ROI indices into (batch, y-band, x-band) buckets.
// ---------------------------------------------------------------------------
__global__ __launch_bounds__(1024) void bucket_rois_kernel(
    const float* __restrict__ rois, int* __restrict__ order)
{
    __shared__ int cnt[1024];
    const int t = threadIdx.x;
    cnt[t] = 0;
    __syncthreads();

    int k = 0, pos = 0;
    if (t < R) {
        const float* roi = rois + t * 5;
        const int   b  = (int)roi[0];
        const float cx = 0.5f * (roi[1] + roi[3]);
        const float cy = 0.5f * (roi[2] + roi[4]);
        const int yb = min(NYB - 1, max(0, (int)cy >> 6));
        const int xb = min(NXB - 1, max(0, (int)cx >> 6));
        k = (b * NYB + yb) * NXB + xb;
        pos = atomicAdd(&cnt[k], 1);      // rank within bucket
    }
    __syncthreads();

    // Inclusive Hillis-Steele scan over the 1024 bucket counts.
    for (int off = 1; off < 1024; off <<= 1) {
        const int add = (t >= off) ? cnt[t - off] : 0;
        __syncthreads();
        cnt[t] += add;
        __syncthreads();
    }

    if (t < R) {
        const int base = (k > 0) ? cnt[k - 1] : 0;  // exclusive prefix
        order[base + pos] = t;
    }
}

// ---------------------------------------------------------------------------
// Kernel B: ROI-Align via LDS rect staging.
// R0-R3 showed dur pinned at ~170-190us across wildly different schedules and
// MLP depths: the wall is the SHAPE of the traffic (100M divergent 8B gathers
// fragmenting into partial-line transactions), not bytes or wave latency.
// This version converts all global reads into coalesced sequential row runs:
//   per channel: stage ROI bounding rect into LDS (contiguous rows),
//   then the 4-corner bilinear gather hits LDS instead of the vmem path.
// Geometry is thread==sample and lives in registers across all 16 channels.
// ---------------------------------------------------------------------------
__global__ __launch_bounds__(256) void roi_align_kernel(
    const float* __restrict__ feat,   // (B, C, H, W)
    const float* __restrict__ rois,   // (R, 5)
    const int*  __restrict__ order,   // (R) spatially bucketed ROI indices
    float* __restrict__ out)          // (R, C, OH, OW)
{
    __shared__ float rect[RECT_ELEMS];
    __shared__ int   sred[4];         // pxmin, pxmax, cy0min, cy1max

    const int bid   = blockIdx.x;
    const int xcd   = bid & (NXCD - 1);       // dispatch round-robins XCDs
    const int slot  = bid >> 3;               // 0..(RPX*CSPLIT-1)
    const int slice = slot & (CSPLIT - 1);    // slice inner: all 16 slices of
    const int rank  = slot >> 4;              // adjacent ROIs co-resident
    const int r     = __builtin_amdgcn_readfirstlane(order[xcd * RPX + rank]);
    const int c0    = slice * CPB;
    const int tid   = threadIdx.x;
    const int lane  = tid & 63;

    const float* roi = rois + r * 5;
    const float x1 = roi[1], y1 = roi[2], x2 = roi[3], y2 = roi[4];
    const int b = __builtin_amdgcn_readfirstlane((int)roi[0]);

    // ---- per-sample geometry, kept in registers (thread == sample) ----
    int px = 0, cy0 = 0, cy1 = 0;
    float wa0 = 0.f, wb0 = 0.f, wa1 = 0.f, wb1 = 0.f;
    int mnpx = INT_MAX, mxpx = INT_MIN, mncy = INT_MAX, mxcy = INT_MIN;

    if (tid < OHW) {
        const int oh = tid / OW;
        const int ow = tid - oh * OW;

        // Sample position in feature space (matches reference exactly)
        const float fx = (x1 + (ow + 0.5f) * (1.0f / OW) * (x2 - x1)) * SCALE - 0.5f;
        const float fy = (y1 + (oh + 0.5f) * (1.0f / OH) * (y2 - y1)) * SCALE - 0.5f;

        const float x0f = floorf(fx), y0f = floorf(fy);
        const float lx = fx - x0f,   ly = fy - y0f;
        const int x0 = (int)x0f,  y0 = (int)y0f;
        const int x1i = x0 + 1,   y1i = y0 + 1;

        // Validity folded into weights (reference: v * valid)
        const float cxw0 = ((x0  >= 0 && x0  < W) ? 1.0f : 0.0f) * (1.0f - lx);
        const float cxw1 = ((x1i >= 0 && x1i < W) ? 1.0f : 0.0f) * lx;
        const float ryw0 = ((y0  >= 0 && y0  < H) ? 1.0f : 0.0f) * (1.0f - ly);
        const float ryw1 = ((y1i >= 0 && y1i < H) ? 1.0f : 0.0f) * ly;

        // Pair base clamped so [px, px+1] stays in-row; pre-swap weights if
        // clamped (invalid corner's weight is already 0, so swap is lossless).
        px = min(max(x0, 0), W - 2);
        const bool swp = (x0 != px);
        const float wxa = swp ? cxw1 : cxw0;
        const float wxb = swp ? cxw0 : cxw1;
        wa0 = ryw0 * wxa; wb0 = ryw0 * wxb;
        wa1 = ryw1 * wxa; wb1 = ryw1 * wxb;

        cy0 = min(max(y0,  0), H - 1);
        cy1 = min(max(y1i, 0), H - 1);

        mnpx = px; mxpx = px; mncy = cy0; mxcy = cy1;
    }

    // ---- block-wide min/max reduction for the bounding rect ----
    #pragma unroll
    for (int o = 32; o; o >>= 1) {
        mnpx = min(mnpx, __shfl_xor(mnpx, o));
        mxpx = max(mxpx, __shfl_xor(mxpx, o));
        mncy = min(mncy, __shfl_xor(mncy, o));
        mxcy = max(mxcy, __shfl_xor(mxcy, o));
    }
    if (tid == 0) { sred[0] = INT_MAX; sred[1] = INT_MIN;
                    sred[2] = INT_MAX; sred[3] = INT_MIN; }
    __syncthreads();
    if (lane == 0) {
        atomicMin(&sred[0], mnpx); atomicMax(&sred[1], mxpx);
        atomicMin(&sred[2], mncy); atomicMax(&sred[3], mxcy);
    }
    __syncthreads();
    const int pxmin = sred[0], pxmax = sred[1];
    const int cymin = sred[2], cymax = sred[3];
    const int rw  = pxmax + 2 - pxmin;        // cols incl. +1 corner, <= 66
    const int rws = rw | 1;                   // odd LDS stride, <= 67
    const int rh  = cymax + 1 - cymin;        // rows, <= 66
    const int total = rh * rws;
    // Exact unsigned magic divide by odd rws (valid for i << 2^32/rws)
    const unsigned minv = 0xFFFFFFFFu / (unsigned)rws + 1u;

    // Rect-relative corner indices (registers, reused for all 16 channels)
    int i0 = 0, i1 = 0;
    if (tid < OHW) {
        i0 = (cy0 - cymin) * rws + (px - pxmin);
        i1 = (cy1 - cymin) * rws + (px - pxmin);
    }

    const float* pc = feat + (size_t)(b * C + c0) * HW
                           + (size_t)cymin * W + pxmin;
    float* ob = out + ((size_t)r * C + c0) * OHW;

    for (int c = 0; c < CPB; ++c) {
        // ---- stage rect: contiguous per-row runs, fully coalesced ----
        #pragma unroll 2
        for (int i = tid; i < total; i += 256) {
            const int row = (int)__umulhi((unsigned)i, minv);
            const int col = i - row * rws;
            // pad col (rws > rw: at most 1) duplicates last col; never read
            rect[i] = pc[row * W + min(col, rw - 1)];
        }
        __syncthreads();
        // ---- bilinear from LDS; store contiguous 196-float run ----
        if (tid < OHW) {
            const float v = fmaf(wa0, rect[i0],
                            fmaf(wb0, rect[i0 + 1],
                            fmaf(wa1, rect[i1], wb1 * rect[i1 + 1])));
            __builtin_nontemporal_store(v, ob + tid);
        }
        __syncthreads();
        pc += HW;
        ob += OHW;
    }
}

extern "C" void kernel_launch(void* const* d_in, const int* in_sizes, int n_in,
                              void* d_out, int out_size, void* d_ws, size_t ws_size,
                              hipStream_t stream) {
    const float* feat = (const float*)d_in[0];
    const float* rois = (const float*)d_in[1];
    float* out = (float*)d_out;
    int* order = (int*)d_ws;         // R ints of scratch

    bucket_rois_kernel<<<1, 1024, 0, stream>>>(rois, order);

    dim3 grid(R * CSPLIT);
    dim3 block(256);
    roi_align_kernel<<<grid, block, 0, stream>>>(feat, rois, order, out);
}